// Round 11
// baseline (143.573 us; speedup 1.0000x reference)
//
#include <hip/hip_runtime.h>
#include <hip/hip_fp16.h>

#define NB 2049
#define TF 600
#define WINF 300
#define NFFT 4096
#define HOP 1024
#define ALEN 613376
#define EPSV 1e-10f
#define SQEPS 1e-5f
#define RCH 60
#define RCHT 5
#define ROWZ 2048             // half2 per Z/frame row (8192 B)
#define W4096 0.0015339807878856412f   /* 2*pi/4096 */

// LDS padding: floor bank distribution for every Stockham access pattern.
#define PADI(i) ((i) + ((i) >> 4))

__device__ __forceinline__ float2 cmul(float2 a, float2 b) {
  return make_float2(a.x*b.x - a.y*b.y, a.x*b.y + a.y*b.x);
}
__device__ __forceinline__ float2 cadd(float2 a, float2 b) {
  return make_float2(a.x + b.x, a.y + b.y);
}
__device__ __forceinline__ float2 csub(float2 a, float2 b) {
  return make_float2(a.x - b.x, a.y - b.y);
}

__device__ __forceinline__ float2 h2f2(unsigned w) {
  union { unsigned u; __half2 h; } c; c.u = w;
  return __half22float2(c.h);
}

__global__ __launch_bounds__(256) void k_init(unsigned int* c2max) {
  if (blockIdx.x == 0 && threadIdx.x < 4) c2max[threadIdx.x] = 0u;
}

// ---- K1 (fallback only): per-window max |mix|^2 ---------------------------
__global__ __launch_bounds__(256) void k_maxred(const float* __restrict__ mix,
                                                unsigned int* __restrict__ c2max) {
  int winid = blockIdx.x >> 6;
  int blk = blockIdx.x & 63;
  const float4* p = (const float4*)(mix + (size_t)winid * (WINF * NB * 2 * 2));
  const int n4 = WINF * NB * 2 * 2 / 4;
  float m = 0.f;
  for (int i = blk * 256 + threadIdx.x; i < n4; i += 64 * 256) {
    float4 v = p[i];
    m = fmaxf(m, fmaxf(v.x*v.x + v.y*v.y, v.z*v.z + v.w*v.w));
  }
  for (int off = 32; off; off >>= 1) m = fmaxf(m, __shfl_xor(m, off));
  __shared__ float sm[4];
  if ((threadIdx.x & 63) == 0) sm[threadIdx.x >> 6] = m;
  __syncthreads();
  if (threadIdx.x == 0) {
    m = fmaxf(fmaxf(sm[0], sm[1]), fmaxf(sm[2], sm[3]));
    atomicMax(c2max + winid, __float_as_uint(m));
  }
}

// ---- K2a: covariance partials, lane = f (coalesced) + fused |mix|^2 max ---
// 2160 blocks (8.4/CU); RCHT=5 t-loop fully unrolled -> 15 independent loads
// in flight per thread (latency hiding via MLP, not occupancy alone).
__global__ __launch_bounds__(256) void k_rmat_part(const float* __restrict__ spec,
                                                   const float* __restrict__ mix,
                                                   float* __restrict__ part,
                                                   unsigned int* __restrict__ c2max) {
  int ftile = blockIdx.x % 9;
  int chunk = (blockIdx.x / 9) % RCH;
  int winid = blockIdx.x / (9 * RCH);
  int f = ftile * 256 + threadIdx.x;
  const bool act = (f < NB);
  int b = winid >> 1, w = winid & 1;
  float acc[16];
#pragma unroll
  for (int i = 0; i < 16; i++) acc[i] = 0.f;
  float mx2 = 0.f;
  if (act) {
#pragma unroll
    for (int tt = 0; tt < RCHT; tt++) {
      int t = w * WINF + chunk * RCHT + tt;
      size_t base = (size_t)(b * TF + t) * NB + f;
      const float4* sp = (const float4*)(spec + base * 8);
      float4 s0 = sp[0], s1 = sp[1];
      float4 mx = *(const float4*)(mix + base * 4);
      float n0 = mx.x*mx.x + mx.y*mx.y;
      float n1 = mx.z*mx.z + mx.w*mx.w;
      mx2 = fmaxf(mx2, fmaxf(n0, n1));
      float qr, qi;
      if (n0 > 0.f && n1 > 0.f) {
        float inv = rsqrtf(n0 * n1);
        qr = (mx.x*mx.z + mx.y*mx.w) * inv;
        qi = (mx.y*mx.z - mx.x*mx.w) * inv;
      } else if (n0 > 0.f) { float inv = rsqrtf(n0); qr = mx.x*inv; qi = mx.y*inv; }
      else if (n1 > 0.f)   { float inv = rsqrtf(n1); qr = mx.z*inv; qi = -mx.w*inv; }
      else { qr = 1.f; qi = 0.f; }
      float A0[4] = {s0.x, s0.y, s0.z, s0.w};
      float A1[4] = {s1.x, s1.y, s1.z, s1.w};
#pragma unroll
      for (int s = 0; s < 4; s++) {
        acc[s*4+0] += A0[s]*A0[s];
        acc[s*4+1] += A1[s]*A1[s];
        float aa = A0[s]*A1[s];
        acc[s*4+2] += aa * qr;
        acc[s*4+3] += aa * qi;
      }
    }
    float* pp = part + (((size_t)winid * RCH + chunk) * NB + f) * 16;
#pragma unroll
    for (int s = 0; s < 4; s++)
      *(float4*)(pp + s*4) = make_float4(acc[s*4+0], acc[s*4+1], acc[s*4+2], acc[s*4+3]);
  }
  // block-level max -> atomicMax (all threads participate)
  for (int off = 32; off; off >>= 1) mx2 = fmaxf(mx2, __shfl_xor(mx2, off));
  __shared__ float sm[4];
  if ((threadIdx.x & 63) == 0) sm[threadIdx.x >> 6] = mx2;
  __syncthreads();
  if (threadIdx.x == 0) {
    mx2 = fmaxf(fmaxf(sm[0], sm[1]), fmaxf(sm[2], sm[3]));
    atomicMax(c2max + winid, __float_as_uint(mx2));
  }
}

// ---- K2b: reduce partials + normalize -> Rbuf -----------------------------
__global__ __launch_bounds__(256) void k_rmat_red(const float* __restrict__ part,
                                                  const unsigned int* __restrict__ c2max,
                                                  float* __restrict__ Rbuf) {
  int idx = blockIdx.x * 256 + threadIdx.x;
  if (idx >= 4 * NB * 4) return;
  int s = idx & 3;
  int f = (idx >> 2) % NB;
  int winid = idx / (NB * 4);
  float4 a = make_float4(0.f, 0.f, 0.f, 0.f);
#pragma unroll
  for (int ch = 0; ch < RCH; ch++) {
    float4 p = *(const float4*)(part + (((size_t)winid * RCH + ch) * NB + f) * 16 + s * 4);
    a.x += p.x; a.y += p.y; a.z += p.z; a.w += p.w;
  }
  float c = fmaxf(1.f, sqrtf(__uint_as_float(c2max[winid])) * 0.1f);
  float W = c * c * EPSV + 0.5f * (a.x + a.y);
  float invW = 1.f / W;
  *(float4*)(Rbuf + ((size_t)winid * NB + f) * 16 + s * 4) =
      make_float4(a.x*invW, a.y*invW, a.z*invW, a.w*invW);
}

// ---- legacy K2 (fallback only) --------------------------------------------
__global__ __launch_bounds__(256) void k_rmat(const float* __restrict__ spec,
                                              const float* __restrict__ mix,
                                              const unsigned int* __restrict__ c2max,
                                              float* __restrict__ Rbuf) {
  int f = blockIdx.x;
  int winid = threadIdx.x >> 6;
  int lane = threadIdx.x & 63;
  int b = winid >> 1, w = winid & 1;
  float acc[16];
#pragma unroll
  for (int i = 0; i < 16; i++) acc[i] = 0.f;
  for (int tl = lane; tl < WINF; tl += 64) {
    int t = w * WINF + tl;
    size_t base = (size_t)(b * TF + t) * NB + f;
    const float4* sp = (const float4*)(spec + base * 8);
    float4 s0 = sp[0], s1 = sp[1];
    float4 mx = *(const float4*)(mix + base * 4);
    float n0 = mx.x*mx.x + mx.y*mx.y;
    float n1 = mx.z*mx.z + mx.w*mx.w;
    float qr, qi;
    if (n0 > 0.f && n1 > 0.f) {
      float inv = rsqrtf(n0 * n1);
      qr = (mx.x*mx.z + mx.y*mx.w) * inv;
      qi = (mx.y*mx.z - mx.x*mx.w) * inv;
    } else if (n0 > 0.f) { float inv = rsqrtf(n0); qr = mx.x*inv; qi = mx.y*inv; }
    else if (n1 > 0.f)   { float inv = rsqrtf(n1); qr = mx.z*inv; qi = -mx.w*inv; }
    else { qr = 1.f; qi = 0.f; }
    float A0[4] = {s0.x, s0.y, s0.z, s0.w};
    float A1[4] = {s1.x, s1.y, s1.z, s1.w};
#pragma unroll
    for (int s = 0; s < 4; s++) {
      acc[s*4+0] += A0[s]*A0[s];
      acc[s*4+1] += A1[s]*A1[s];
      float aa = A0[s]*A1[s];
      acc[s*4+2] += aa * qr;
      acc[s*4+3] += aa * qi;
    }
  }
#pragma unroll
  for (int i = 0; i < 16; i++) {
#pragma unroll
    for (int off = 32; off; off >>= 1) acc[i] += __shfl_xor(acc[i], off);
  }
  if (lane == 0) {
    float c = fmaxf(1.f, sqrtf(__uint_as_float(c2max[winid])) * 0.1f);
    float c2 = c * c;
#pragma unroll
    for (int s = 0; s < 4; s++) {
      float W = c2 * EPSV + 0.5f * (acc[s*4+0] + acc[s*4+1]);
      float invW = 1.f / W;
      *(float4*)(Rbuf + ((size_t)winid * NB + f) * 16 + s * 4) =
          make_float4(acc[s*4+0]*invW, acc[s*4+1]*invW, acc[s*4+2]*invW, acc[s*4+3]*invW);
    }
  }
}

// ---- EM solve at one (b,t,f): all 8 (source,channel) outputs --------------
__device__ __forceinline__ void em8(const float* __restrict__ spec,
                                    const float* __restrict__ mix,
                                    const float* __restrict__ Rbuf,
                                    int winid, float c, float invc, float inv2c2,
                                    size_t base, int f, float2* y) {
  const float4* sp = (const float4*)(spec + base * 8);
  float4 s0v = sp[0], s1v = sp[1];
  float4 mx = *(const float4*)(mix + base * 4);
  const float4* Rp = (const float4*)(Rbuf + ((size_t)winid * NB + f) * 16);
  float A0[4] = {s0v.x, s0v.y, s0v.z, s0v.w};
  float A1[4] = {s1v.x, s1v.y, s1v.z, s1v.w};
  float v[4]; float4 R[4];
  float C00 = SQEPS, C11 = SQEPS, C01r = 0.f, C01i = 0.f;
#pragma unroll
  for (int sq = 0; sq < 4; sq++) {
    R[sq] = Rp[sq];
    v[sq] = (A0[sq]*A0[sq] + A1[sq]*A1[sq]) * inv2c2;
    C00 += v[sq]*R[sq].x; C11 += v[sq]*R[sq].y;
    C01r += v[sq]*R[sq].z; C01i += v[sq]*R[sq].w;
  }
  float det = C00*C11 - (C01r*C01r + C01i*C01i);
  float invdet = 1.f / det;
  float x0r = mx.x*invc, x0i = mx.y*invc, x1r = mx.z*invc, x1i = mx.w*invc;
  float ix0r = (C11*x0r - (C01r*x1r - C01i*x1i)) * invdet;
  float ix0i = (C11*x0i - (C01r*x1i + C01i*x1r)) * invdet;
  float ix1r = (C00*x1r - (C01r*x0r + C01i*x0i)) * invdet;
  float ix1i = (C00*x1i - (C01r*x0i - C01i*x0r)) * invdet;
#pragma unroll
  for (int sq = 0; sq < 4; sq++) {
    float vc = v[sq] * c;
    y[sq*2+0] = make_float2(vc*(R[sq].x*ix0r + R[sq].z*ix1r - R[sq].w*ix1i),
                            vc*(R[sq].x*ix0i + R[sq].z*ix1i + R[sq].w*ix1r));
    y[sq*2+1] = make_float2(vc*(R[sq].z*ix0r + R[sq].w*ix0i + R[sq].y*ix1r),
                            vc*(R[sq].z*ix0i - R[sq].w*ix0r + R[sq].y*ix1i));
  }
}

// ---- K3: EM apply + Hermitian fold, write Z (fp16), row stride ROWZ -------
__global__ __launch_bounds__(256) void k_apply(const float* __restrict__ spec,
                                               const float* __restrict__ mix,
                                               const unsigned int* __restrict__ c2max,
                                               const float* __restrict__ Rbuf,
                                               __half2* __restrict__ Z) {
  size_t idx = (size_t)blockIdx.x * 256 + threadIdx.x;
  if (idx >= (size_t)2 * TF * 1025) return;
  int k = (int)(idx % 1025);
  int r = (int)(idx / 1025);
  int t = r % TF, b = r / TF;
  int winid = b * 2 + (t >= WINF ? 1 : 0);
  float c = fmaxf(1.f, sqrtf(__uint_as_float(c2max[winid])) * 0.1f);
  float invc = 1.f / c, inv2c2 = 0.5f * invc * invc;
  size_t rowb = (size_t)(b * TF + t) * NB;
  int fB = 2048 - k;
  float2 yA[8], yB[8];
  em8(spec, mix, Rbuf, winid, c, invc, inv2c2, rowb + k,  k,  yA);
  em8(spec, mix, Rbuf, winid, c, invc, inv2c2, rowb + fB, fB, yB);
  float sn, cs;
  __sincosf((float)k * 0.0015339807878856412f /* pi/2048 */, &sn, &cs);
#pragma unroll
  for (int o = 0; o < 8; o++) {
    float2 Xa = yA[o], Xb = yB[o];
    if (k == 0) { Xa.y = 0.f; Xb.y = 0.f; }
    float Sx = Xa.x + Xb.x, Sy = Xa.y - Xb.y;
    float Dx = Xa.x - Xb.x, Dy = Xa.y + Xb.y;
    float sd = sn*Dx, cd = cs*Dy;
    float ci = cs*Dx - sn*Dy;
    int sid = (b * 4 + (o >> 1)) * 2 + (o & 1);
    size_t rowo = ((size_t)sid * TF + t) * ROWZ;
    Z[rowo + k] = __floats2half2_rn(0.5f*(Sx - sd - cd), 0.5f*(Sy + ci));
    if (k > 0)
      Z[rowo + 2048 - k] = __floats2half2_rn(0.5f*(Sx + sd + cd), 0.5f*(-Sy + ci));
  }
}

// ---- inverse DFT-8 (unnormalized, e^{+i}) ---------------------------------
__device__ __forceinline__ void dft8(const float2* x, float2* X) {
  const float S2 = 0.70710678118654752f;
  float2 t0 = cadd(x[0], x[4]), t1 = csub(x[0], x[4]);
  float2 t2 = cadd(x[2], x[6]), t3 = csub(x[2], x[6]);
  float2 E0 = cadd(t0, t2), E2 = csub(t0, t2);
  float2 E1 = make_float2(t1.x - t3.y, t1.y + t3.x);
  float2 E3 = make_float2(t1.x + t3.y, t1.y - t3.x);
  float2 u0 = cadd(x[1], x[5]), u1 = csub(x[1], x[5]);
  float2 u2 = cadd(x[3], x[7]), u3 = csub(x[3], x[7]);
  float2 O0 = cadd(u0, u2), O2 = csub(u0, u2);
  float2 O1 = make_float2(u1.x - u3.y, u1.y + u3.x);
  float2 O3 = make_float2(u1.x + u3.y, u1.y - u3.x);
  float2 R1 = make_float2(S2*(O1.x - O1.y), S2*(O1.x + O1.y));   // e^{i pi/4} O1
  float2 R2 = make_float2(-O2.y, O2.x);                          // i O2
  float2 R3 = make_float2(-S2*(O3.x + O3.y), S2*(O3.x - O3.y));  // e^{i 3pi/4} O3
  X[0] = cadd(E0, O0); X[4] = csub(E0, O0);
  X[1] = cadd(E1, R1); X[5] = csub(E1, R1);
  X[2] = cadd(E2, R2); X[6] = csub(E2, R2);
  X[3] = cadd(E3, R3); X[7] = csub(E3, R3);
}

// radix-8 Stockham stage from registers, NS=1 (no twiddles)
__device__ __forceinline__ void r8_reg(const float2* x, float2* dst, int tid) {
  float2 X[8];
  dft8(x, X);
  const int d = tid << 3;
#pragma unroll
  for (int n = 0; n < 8; n++) dst[PADI(d + n)] = X[n];
}

// radix-8 Stockham stage, IN PLACE, twiddles from LDS table
// tw[jm*7 + (m-1)] = e^{i*pi*jm*m/(4*NS)}
template<int NS>
__device__ __forceinline__ void r8stage_ip_t(float2* __restrict__ buf,
                                             const float2* __restrict__ tw, int tid) {
  const int q = tid;
  const int jm = q & (NS - 1);
  float2 x[8];
#pragma unroll
  for (int m = 0; m < 8; m++) x[m] = buf[PADI(q + (m << 8))];
  const float2* tr = tw + jm * 7;
#pragma unroll
  for (int m = 1; m < 8; m++) x[m] = cmul(x[m], tr[m - 1]);
  float2 X[8];
  dft8(x, X);
  __syncthreads();   // all reads complete before any write (same buffer)
  const int d = ((q - jm) << 3) + jm;
#pragma unroll
  for (int n = 0; n < 8; n++) buf[PADI(d + n * NS)] = X[n];
}

// final radix-4 stage (NS=512) + Hann window + fp16 store (registers only)
__device__ __forceinline__ void r4_final(const float2* __restrict__ src,
                                         __half2* __restrict__ frow, int tid) {
  const float S2 = 0.70710678118654752f;
  // window weights (x 1/2048) for n2 = tid + 256*m, m=0..7; chained rotation pi/4
  float we[8], wo[8];
  float bsn, bcs;
  __sincosf((float)tid * 0.0030679615757712823f /* 2pi/2048 */, &bsn, &bcs);
  {
    float cs = bcs, sn = bsn;
    const float CD = 0.9999988234517019f, SD = 0.0015339801862847657f; // 2pi/4096
#pragma unroll
    for (int m = 0; m < 8; m++) {
      we[m] = (0.5f - 0.5f*cs) * (1.f/2048.f);
      float c1 = cs*CD - sn*SD;
      wo[m] = (0.5f - 0.5f*c1) * (1.f/2048.f);
      float ncs = (cs - sn) * S2;
      float nsn = (sn + cs) * S2;
      cs = ncs; sn = nsn;
    }
  }
  float2 w1 = make_float2(bcs, bsn);   // e^{i q pi/1024}, q=tid
#pragma unroll
  for (int qq = 0; qq < 2; qq++) {
    const int q = tid + (qq << 8);
    float2 v0 = src[PADI(q)];
    float2 v1 = src[PADI(q + 512)];
    float2 v2 = src[PADI(q + 1024)];
    float2 v3 = src[PADI(q + 1536)];
    float2 w2 = cmul(w1, w1);
    float2 w3 = cmul(w2, w1);
    v1 = cmul(v1, w1);
    v2 = cmul(v2, w2);
    v3 = cmul(v3, w3);
    float2 t0 = cadd(v0, v2), t1 = csub(v0, v2);
    float2 t2 = cadd(v1, v3), t3 = csub(v1, v3);
    float2 X0 = cadd(t0, t2);
    float2 X1 = make_float2(t1.x - t3.y, t1.y + t3.x);
    float2 X2 = csub(t0, t2);
    float2 X3 = make_float2(t1.x + t3.y, t1.y - t3.x);
    frow[q]        = __floats2half2_rn(X0.x*we[qq],     X0.y*wo[qq]);
    frow[q + 512]  = __floats2half2_rn(X1.x*we[qq + 2], X1.y*wo[qq + 2]);
    frow[q + 1024] = __floats2half2_rn(X2.x*we[qq + 4], X2.y*wo[qq + 4]);
    frow[q + 1536] = __floats2half2_rn(X3.x*we[qq + 6], X3.y*wo[qq + 6]);
    if (qq == 0)
      w1 = make_float2((w1.x - w1.y) * S2, (w1.y + w1.x) * S2); // *= e^{i pi/4}
  }
}

// ---- K4a: one block per (sid, t): ifft of prefolded Z (radix 8,8,8,4) -----
__global__ __launch_bounds__(256, 6) void k_frames(__half2* __restrict__ ZF) {
  __shared__ float2 buf[2176];
  __shared__ float2 tw[504];
  const int tid = threadIdx.x;
  const int t = blockIdx.x % TF;
  const int sid = blockIdx.x / TF;
  const size_t row = ((size_t)sid * TF + t) * ROWZ;
  const unsigned* Zu = (const unsigned*)(ZF + row);

  // build twiddle table (once per block; visibility covered by sync below)
  for (int i = tid; i < 504; i += 256) {
    int jm, m; float scale;
    if (i < 56)  { jm = i / 7;        m = i % 7 + 1; scale = 0.09817477042468103f; }  // pi/32
    else         { int j = i - 56; jm = j / 7; m = j % 7 + 1; scale = 0.012271846303085129f; } // pi/256
    float sn, cs;
    __sincosf((float)(jm * m) * scale, &sn, &cs);
    tw[i] = make_float2(cs, sn);
  }

  // load prefolded Z straight into registers (coalesced)
  float2 x[8];
#pragma unroll
  for (int m = 0; m < 8; m++) x[m] = h2f2(Zu[tid + (m << 8)]);

  r8_reg(x, buf, tid);     // NS=1 write (no prior LDS content)
  __syncthreads();         // covers table build + buf
  r8stage_ip_t<8>(buf, tw, tid);
  __syncthreads();
  r8stage_ip_t<64>(buf, tw + 56, tid);
  __syncthreads();
  r4_final(buf, ZF + row, tid);   // NS=512 + window + store (in-place row)
}

// ---- K4b: gather overlap-add (4 frames) + wsum normalize, float4 stores ---
__global__ __launch_bounds__(256) void k_gather(const __half2* __restrict__ frames,
                                                float* __restrict__ out) {
  const int sid = blockIdx.x / 599;
  const int o4 = (blockIdx.x % 599) * 256 + threadIdx.x;   // 153344 quads/sid
  const int n = 2048 + 4 * o4;
  const int tbase = n >> 10;
  float s0 = 0.f, s1 = 0.f, s2 = 0.f, s3 = 0.f;
#pragma unroll
  for (int dt = 0; dt < 4; dt++) {
    int t = tbase - 3 + dt;
    if ((unsigned)t < (unsigned)TF) {
      int j2 = (n - (t << 10)) >> 1;   // even -> 8B-aligned pair
      float2 pk = *(const float2*)(frames + ((size_t)sid * TF + t) * ROWZ + j2);
      float2 va = h2f2(__float_as_uint(pk.x));
      float2 vb = h2f2(__float_as_uint(pk.y));
      s0 += va.x; s1 += va.y; s2 += vb.x; s3 += vb.y;
    }
  }
  float i0, i1, i2, i3;
  if (tbase >= 3 && tbase <= 599) {
    i0 = i1 = i2 = i3 = 2.f / 3.f;     // wsum exactly 1.5 interior
  } else {
    float w0 = 0.f, w1 = 0.f, w2 = 0.f, w3 = 0.f;
#pragma unroll
    for (int dt = 0; dt < 4; dt++) {
      int t = tbase - 3 + dt;
      if ((unsigned)t < (unsigned)TF) {
        int j = n - (t << 10);
        float a0 = 0.5f - 0.5f * __cosf((float)j * W4096);
        float a1 = 0.5f - 0.5f * __cosf((float)(j + 1) * W4096);
        float a2 = 0.5f - 0.5f * __cosf((float)(j + 2) * W4096);
        float a3 = 0.5f - 0.5f * __cosf((float)(j + 3) * W4096);
        w0 += a0*a0; w1 += a1*a1; w2 += a2*a2; w3 += a3*a3;
      }
    }
    i0 = 1.f / ((w0 > 1e-11f) ? w0 : 1.f);
    i1 = 1.f / ((w1 > 1e-11f) ? w1 : 1.f);
    i2 = 1.f / ((w2 > 1e-11f) ? w2 : 1.f);
    i3 = 1.f / ((w3 > 1e-11f) ? w3 : 1.f);
  }
  *(float4*)(out + (size_t)sid * ALEN + 4 * o4) =
      make_float4(s0 * i0, s1 * i1, s2 * i2, s3 * i3);
}

// ---- legacy fused path (fallback if ws too small) -------------------------
__device__ __forceinline__ float2 em_point_one(const float* __restrict__ spec,
    const float* __restrict__ mix, const float* __restrict__ Rbuf,
    const unsigned int* __restrict__ c2max, int b, int t, int f, int ssel, int ch) {
  int winid = b * 2 + (t >= WINF ? 1 : 0);
  float c = fmaxf(1.f, sqrtf(__uint_as_float(c2max[winid])) * 0.1f);
  float invc = 1.f / c, inv2c2 = 0.5f * invc * invc;
  size_t base = (size_t)(b * TF + t) * NB + f;
  const float4* sp = (const float4*)(spec + base * 8);
  float4 s0 = sp[0], s1 = sp[1];
  float4 mx = *(const float4*)(mix + base * 4);
  const float4* Rp = (const float4*)(Rbuf + ((size_t)winid * NB + f) * 16);
  float A0v[4] = {s0.x, s0.y, s0.z, s0.w};
  float A1v[4] = {s1.x, s1.y, s1.z, s1.w};
  float C00 = SQEPS, C11 = SQEPS, C01r = 0.f, C01i = 0.f;
  float vsel = 0.f; float4 Rsel = make_float4(0.f, 0.f, 0.f, 0.f);
#pragma unroll
  for (int sq = 0; sq < 4; sq++) {
    float4 R = Rp[sq];
    float v = (A0v[sq]*A0v[sq] + A1v[sq]*A1v[sq]) * inv2c2;
    C00 += v*R.x; C11 += v*R.y; C01r += v*R.z; C01i += v*R.w;
    if (sq == ssel) { vsel = v; Rsel = R; }
  }
  float det = C00*C11 - (C01r*C01r + C01i*C01i);
  float invdet = 1.f / det;
  float x0r = mx.x*invc, x0i = mx.y*invc, x1r = mx.z*invc, x1i = mx.w*invc;
  float ix0r = (C11*x0r - (C01r*x1r - C01i*x1i)) * invdet;
  float ix0i = (C11*x0i - (C01r*x1i + C01i*x1r)) * invdet;
  float ix1r = (C00*x1r - (C01r*x0r + C01i*x0i)) * invdet;
  float ix1i = (C00*x1i - (C01r*x0i - C01i*x0r)) * invdet;
  float vc = vsel * c;
  if (ch == 0)
    return make_float2(vc*(Rsel.x*ix0r + Rsel.z*ix1r - Rsel.w*ix1i),
                       vc*(Rsel.x*ix0i + Rsel.z*ix1i + Rsel.w*ix1r));
  return make_float2(vc*(Rsel.z*ix0r + Rsel.w*ix0i + Rsel.y*ix1r),
                     vc*(Rsel.z*ix0i - Rsel.w*ix0r + Rsel.y*ix1i));
}

template<int NS>
__device__ __forceinline__ void r4stage(const float2* __restrict__ src,
                                        float2* __restrict__ dst, int tid) {
#pragma unroll
  for (int qq = 0; qq < 2; qq++) {
    int q = tid + qq * 256;
    int jm = q & (NS - 1);
    float2 v0 = src[PADI(q)];
    float2 v1 = src[PADI(q + 512)];
    float2 v2 = src[PADI(q + 1024)];
    float2 v3 = src[PADI(q + 1536)];
    if constexpr (NS > 1) {
      float sn, cs;
      __sincosf((float)jm * (1.5707963267948966f / (float)NS), &sn, &cs);
      float2 w1 = make_float2(cs, sn);
      float2 w2 = cmul(w1, w1);
      float2 w3 = cmul(w2, w1);
      v1 = cmul(v1, w1);
      v2 = cmul(v2, w2);
      v3 = cmul(v3, w3);
    }
    float2 a0 = cadd(v0, v2), a1 = csub(v0, v2);
    float2 a2 = cadd(v1, v3), a3 = csub(v1, v3);
    int d = ((q - jm) << 2) + jm;
    dst[PADI(d)]        = cadd(a0, a2);
    dst[PADI(d + NS)]   = make_float2(a1.x - a3.y, a1.y + a3.x);
    dst[PADI(d + 2*NS)] = csub(a0, a2);
    dst[PADI(d + 3*NS)] = make_float2(a1.x + a3.y, a1.y - a3.x);
  }
}

__device__ __forceinline__ void r2stage(const float2* __restrict__ src,
                                        float2* __restrict__ dst, int tid) {
#pragma unroll
  for (int qq = 0; qq < 4; qq++) {
    int q = tid + qq * 256;
    float sn, cs;
    __sincosf((float)q * 0.003067961575771282f, &sn, &cs);
    float2 v0 = src[PADI(q)];
    float2 v1 = cmul(src[PADI(q + 1024)], make_float2(cs, sn));
    dst[PADI(q)]        = cadd(v0, v1);
    dst[PADI(q + 1024)] = csub(v0, v1);
  }
}

__global__ __launch_bounds__(256) void k_istft_fused(const float* __restrict__ spec,
        const float* __restrict__ mix, const unsigned int* __restrict__ c2max,
        const float* __restrict__ Rbuf, float* __restrict__ out) {
  __shared__ float2 bufA[2176];
  __shared__ float2 bufB[2176];
  const int tid = threadIdx.x;
  const int u = blockIdx.x % 150;
  const int sid = blockIdx.x / 150;
  const int b = sid >> 3;
  const int s = (sid >> 1) & 3;
  const int ch = sid & 1;
  float acc[16], wsm[16];
#pragma unroll
  for (int k = 0; k < 16; k++) { acc[k] = 0.f; wsm[k] = 0.f; }
  const int t0 = max(0, 4 * u - 1);
  const int t1 = min(TF - 1, 4 * u + 5);
  const int M0 = 2048 + u * 4096;
  for (int t = t0; t <= t1; ++t) {
    for (int k = tid; k < 2048; k += 256) {
      float2 Xa = em_point_one(spec, mix, Rbuf, c2max, b, t, k, s, ch);
      float2 Xb = em_point_one(spec, mix, Rbuf, c2max, b, t, 2048 - k, s, ch);
      if (k == 0) { Xa.y = 0.f; Xb.y = 0.f; }
      float Sx = Xa.x + Xb.x, Sy = Xa.y - Xb.y;
      float Dx = Xa.x - Xb.x, Dy = Xa.y + Xb.y;
      float sn, cs;
      __sincosf((float)k * 0.0015339807878856412f, &sn, &cs);
      bufA[PADI(k)] = make_float2(0.5f * (Sx - sn*Dx - cs*Dy),
                                  0.5f * (Sy + cs*Dx - sn*Dy));
    }
    __syncthreads();
    r4stage<1>(bufA, bufB, tid);   __syncthreads();
    r4stage<4>(bufB, bufA, tid);   __syncthreads();
    r4stage<16>(bufA, bufB, tid);  __syncthreads();
    r4stage<64>(bufB, bufA, tid);  __syncthreads();
    r4stage<256>(bufA, bufB, tid); __syncthreads();
    r2stage(bufB, bufA, tid);      __syncthreads();
    const int delta = M0 - t * HOP;
#pragma unroll
    for (int k2 = 0; k2 < 16; k2++) {
      int n = tid + 256 * k2 + delta;
      if (n >= 0 && n < NFFT) {
        float2 z = bufA[PADI(n >> 1)];
        float xn = (n & 1) ? z.y : z.x;
        float wn = 0.5f - 0.5f * __cosf((float)n * W4096);
        acc[k2] += xn * wn * (1.f / 2048.f);
        wsm[k2] += wn * wn;
      }
    }
    __syncthreads();
  }
#pragma unroll
  for (int k2 = 0; k2 < 16; k2++) {
    size_t o = (size_t)u * 4096 + tid + 256 * k2;
    if (o < (size_t)ALEN) {
      float wsv = wsm[k2];
      out[(size_t)sid * ALEN + o] = acc[k2] / (wsv > 1e-11f ? wsv : 1.f);
    }
  }
}

extern "C" void kernel_launch(void* const* d_in, const int* in_sizes, int n_in,
                              void* d_out, int out_size, void* d_ws, size_t ws_size,
                              hipStream_t stream) {
  const float* spec = (const float*)d_in[0];
  const float* mix  = (const float*)d_in[1];
  float* out = (float*)d_out;
  unsigned char* ws = (unsigned char*)d_ws;
  unsigned int* c2max = (unsigned int*)ws;         // 16 B
  float* Rbuf = (float*)(ws + 256);                // 524544 B
  __half2* Z = (__half2*)(ws + 524800);            // 16*600*2048*4 = 78.6 MB
  float* part = (float*)(ws + 524800);             // 31.5 MB, consumed before Z written
  const size_t needZ = 524800 + (size_t)16 * TF * ROWZ * 4;

  k_init<<<1, 256, 0, stream>>>(c2max);
  if (ws_size >= needZ) {
    k_rmat_part<<<4 * RCH * 9, 256, 0, stream>>>(spec, mix, part, c2max);
    k_rmat_red<<<(4 * NB * 4 + 255) / 256, 256, 0, stream>>>(part, c2max, Rbuf);
    int total = 2 * TF * 1025;
    k_apply<<<(total + 255) / 256, 256, 0, stream>>>(spec, mix, c2max, Rbuf, Z);
    k_frames<<<16 * TF, 256, 0, stream>>>(Z);
    k_gather<<<16 * 599, 256, 0, stream>>>(Z, out);
  } else {
    k_maxred<<<256, 256, 0, stream>>>(mix, c2max);
    k_rmat<<<NB, 256, 0, stream>>>(spec, mix, c2max, Rbuf);
    k_istft_fused<<<16 * 150, 256, 0, stream>>>(spec, mix, c2max, Rbuf, out);
  }
}

// Round 12
// 123.146 us; speedup vs baseline: 1.1659x; 1.1659x over previous
//
#include <hip/hip_runtime.h>
#include <hip/hip_fp16.h>

#define NB 2049
#define TF 600
#define WINF 300
#define NFFT 4096
#define HOP 1024
#define ALEN 613376
#define EPSV 1e-10f
#define SQEPS 1e-5f
#define RCH 20
#define RCHT 15
#define ROWZ 2048             // half2 per Z/frame row (8192 B)
#define W4096 0.0015339807878856412f   /* 2*pi/4096 */

// LDS padding: floor bank distribution for every Stockham access pattern.
#define PADI(i) ((i) + ((i) >> 4))

__device__ __forceinline__ float2 cmul(float2 a, float2 b) {
  return make_float2(a.x*b.x - a.y*b.y, a.x*b.y + a.y*b.x);
}
__device__ __forceinline__ float2 cadd(float2 a, float2 b) {
  return make_float2(a.x + b.x, a.y + b.y);
}
__device__ __forceinline__ float2 csub(float2 a, float2 b) {
  return make_float2(a.x - b.x, a.y - b.y);
}

__device__ __forceinline__ float2 h2f2(unsigned w) {
  union { unsigned u; __half2 h; } c; c.u = w;
  return __half22float2(c.h);
}

__global__ __launch_bounds__(256) void k_init(unsigned int* c2max) {
  if (blockIdx.x == 0 && threadIdx.x < 4) c2max[threadIdx.x] = 0u;
}

// ---- K1 (fallback only): per-window max |mix|^2 ---------------------------
__global__ __launch_bounds__(256) void k_maxred(const float* __restrict__ mix,
                                                unsigned int* __restrict__ c2max) {
  int winid = blockIdx.x >> 6;
  int blk = blockIdx.x & 63;
  const float4* p = (const float4*)(mix + (size_t)winid * (WINF * NB * 2 * 2));
  const int n4 = WINF * NB * 2 * 2 / 4;
  float m = 0.f;
  for (int i = blk * 256 + threadIdx.x; i < n4; i += 64 * 256) {
    float4 v = p[i];
    m = fmaxf(m, fmaxf(v.x*v.x + v.y*v.y, v.z*v.z + v.w*v.w));
  }
  for (int off = 32; off; off >>= 1) m = fmaxf(m, __shfl_xor(m, off));
  __shared__ float sm[4];
  if ((threadIdx.x & 63) == 0) sm[threadIdx.x >> 6] = m;
  __syncthreads();
  if (threadIdx.x == 0) {
    m = fmaxf(fmaxf(sm[0], sm[1]), fmaxf(sm[2], sm[3]));
    atomicMax(c2max + winid, __float_as_uint(m));
  }
}

// ---- K2a: covariance partials, lane = f (coalesced) + fused |mix|^2 max ---
// Round-10 config restored (RCH=20, no unroll): rmat_part steady-state was
// ~20-24 us there; round-11's RCH=60+unroll regressed (write traffic + no MLP).
__global__ __launch_bounds__(256) void k_rmat_part(const float* __restrict__ spec,
                                                   const float* __restrict__ mix,
                                                   float* __restrict__ part,
                                                   unsigned int* __restrict__ c2max) {
  int ftile = blockIdx.x % 9;
  int chunk = (blockIdx.x / 9) % RCH;
  int winid = blockIdx.x / (9 * RCH);
  int f = ftile * 256 + threadIdx.x;
  const bool act = (f < NB);
  int b = winid >> 1, w = winid & 1;
  float acc[16];
#pragma unroll
  for (int i = 0; i < 16; i++) acc[i] = 0.f;
  float mx2 = 0.f;
  if (act) {
    for (int tt = 0; tt < RCHT; tt++) {
      int t = w * WINF + chunk * RCHT + tt;
      size_t base = (size_t)(b * TF + t) * NB + f;
      const float4* sp = (const float4*)(spec + base * 8);
      float4 s0 = sp[0], s1 = sp[1];
      float4 mx = *(const float4*)(mix + base * 4);
      float n0 = mx.x*mx.x + mx.y*mx.y;
      float n1 = mx.z*mx.z + mx.w*mx.w;
      mx2 = fmaxf(mx2, fmaxf(n0, n1));
      float qr, qi;
      if (n0 > 0.f && n1 > 0.f) {
        float inv = rsqrtf(n0 * n1);
        qr = (mx.x*mx.z + mx.y*mx.w) * inv;
        qi = (mx.y*mx.z - mx.x*mx.w) * inv;
      } else if (n0 > 0.f) { float inv = rsqrtf(n0); qr = mx.x*inv; qi = mx.y*inv; }
      else if (n1 > 0.f)   { float inv = rsqrtf(n1); qr = mx.z*inv; qi = -mx.w*inv; }
      else { qr = 1.f; qi = 0.f; }
      float A0[4] = {s0.x, s0.y, s0.z, s0.w};
      float A1[4] = {s1.x, s1.y, s1.z, s1.w};
#pragma unroll
      for (int s = 0; s < 4; s++) {
        acc[s*4+0] += A0[s]*A0[s];
        acc[s*4+1] += A1[s]*A1[s];
        float aa = A0[s]*A1[s];
        acc[s*4+2] += aa * qr;
        acc[s*4+3] += aa * qi;
      }
    }
    float* pp = part + (((size_t)winid * RCH + chunk) * NB + f) * 16;
#pragma unroll
    for (int s = 0; s < 4; s++)
      *(float4*)(pp + s*4) = make_float4(acc[s*4+0], acc[s*4+1], acc[s*4+2], acc[s*4+3]);
  }
  // block-level max -> atomicMax (all threads participate)
  for (int off = 32; off; off >>= 1) mx2 = fmaxf(mx2, __shfl_xor(mx2, off));
  __shared__ float sm[4];
  if ((threadIdx.x & 63) == 0) sm[threadIdx.x >> 6] = mx2;
  __syncthreads();
  if (threadIdx.x == 0) {
    mx2 = fmaxf(fmaxf(sm[0], sm[1]), fmaxf(sm[2], sm[3]));
    atomicMax(c2max + winid, __float_as_uint(mx2));
  }
}

// ---- K2b: reduce partials + normalize -> Rbuf -----------------------------
__global__ __launch_bounds__(256) void k_rmat_red(const float* __restrict__ part,
                                                  const unsigned int* __restrict__ c2max,
                                                  float* __restrict__ Rbuf) {
  int idx = blockIdx.x * 256 + threadIdx.x;
  if (idx >= 4 * NB * 4) return;
  int s = idx & 3;
  int f = (idx >> 2) % NB;
  int winid = idx / (NB * 4);
  float4 a = make_float4(0.f, 0.f, 0.f, 0.f);
#pragma unroll
  for (int ch = 0; ch < RCH; ch++) {
    float4 p = *(const float4*)(part + (((size_t)winid * RCH + ch) * NB + f) * 16 + s * 4);
    a.x += p.x; a.y += p.y; a.z += p.z; a.w += p.w;
  }
  float c = fmaxf(1.f, sqrtf(__uint_as_float(c2max[winid])) * 0.1f);
  float W = c * c * EPSV + 0.5f * (a.x + a.y);
  float invW = 1.f / W;
  *(float4*)(Rbuf + ((size_t)winid * NB + f) * 16 + s * 4) =
      make_float4(a.x*invW, a.y*invW, a.z*invW, a.w*invW);
}

// ---- legacy K2 (fallback only) --------------------------------------------
__global__ __launch_bounds__(256) void k_rmat(const float* __restrict__ spec,
                                              const float* __restrict__ mix,
                                              const unsigned int* __restrict__ c2max,
                                              float* __restrict__ Rbuf) {
  int f = blockIdx.x;
  int winid = threadIdx.x >> 6;
  int lane = threadIdx.x & 63;
  int b = winid >> 1, w = winid & 1;
  float acc[16];
#pragma unroll
  for (int i = 0; i < 16; i++) acc[i] = 0.f;
  for (int tl = lane; tl < WINF; tl += 64) {
    int t = w * WINF + tl;
    size_t base = (size_t)(b * TF + t) * NB + f;
    const float4* sp = (const float4*)(spec + base * 8);
    float4 s0 = sp[0], s1 = sp[1];
    float4 mx = *(const float4*)(mix + base * 4);
    float n0 = mx.x*mx.x + mx.y*mx.y;
    float n1 = mx.z*mx.z + mx.w*mx.w;
    float qr, qi;
    if (n0 > 0.f && n1 > 0.f) {
      float inv = rsqrtf(n0 * n1);
      qr = (mx.x*mx.z + mx.y*mx.w) * inv;
      qi = (mx.y*mx.z - mx.x*mx.w) * inv;
    } else if (n0 > 0.f) { float inv = rsqrtf(n0); qr = mx.x*inv; qi = mx.y*inv; }
    else if (n1 > 0.f)   { float inv = rsqrtf(n1); qr = mx.z*inv; qi = -mx.w*inv; }
    else { qr = 1.f; qi = 0.f; }
    float A0[4] = {s0.x, s0.y, s0.z, s0.w};
    float A1[4] = {s1.x, s1.y, s1.z, s1.w};
#pragma unroll
    for (int s = 0; s < 4; s++) {
      acc[s*4+0] += A0[s]*A0[s];
      acc[s*4+1] += A1[s]*A1[s];
      float aa = A0[s]*A1[s];
      acc[s*4+2] += aa * qr;
      acc[s*4+3] += aa * qi;
    }
  }
#pragma unroll
  for (int i = 0; i < 16; i++) {
#pragma unroll
    for (int off = 32; off; off >>= 1) acc[i] += __shfl_xor(acc[i], off);
  }
  if (lane == 0) {
    float c = fmaxf(1.f, sqrtf(__uint_as_float(c2max[winid])) * 0.1f);
    float c2 = c * c;
#pragma unroll
    for (int s = 0; s < 4; s++) {
      float W = c2 * EPSV + 0.5f * (acc[s*4+0] + acc[s*4+1]);
      float invW = 1.f / W;
      *(float4*)(Rbuf + ((size_t)winid * NB + f) * 16 + s * 4) =
          make_float4(acc[s*4+0]*invW, acc[s*4+1]*invW, acc[s*4+2]*invW, acc[s*4+3]*invW);
    }
  }
}

// ---- EM solve at one (b,t,f): all 8 (source,channel) outputs --------------
__device__ __forceinline__ void em8(const float* __restrict__ spec,
                                    const float* __restrict__ mix,
                                    const float* __restrict__ Rbuf,
                                    int winid, float c, float invc, float inv2c2,
                                    size_t base, int f, float2* y) {
  const float4* sp = (const float4*)(spec + base * 8);
  float4 s0v = sp[0], s1v = sp[1];
  float4 mx = *(const float4*)(mix + base * 4);
  const float4* Rp = (const float4*)(Rbuf + ((size_t)winid * NB + f) * 16);
  float A0[4] = {s0v.x, s0v.y, s0v.z, s0v.w};
  float A1[4] = {s1v.x, s1v.y, s1v.z, s1v.w};
  float v[4]; float4 R[4];
  float C00 = SQEPS, C11 = SQEPS, C01r = 0.f, C01i = 0.f;
#pragma unroll
  for (int sq = 0; sq < 4; sq++) {
    R[sq] = Rp[sq];
    v[sq] = (A0[sq]*A0[sq] + A1[sq]*A1[sq]) * inv2c2;
    C00 += v[sq]*R[sq].x; C11 += v[sq]*R[sq].y;
    C01r += v[sq]*R[sq].z; C01i += v[sq]*R[sq].w;
  }
  float det = C00*C11 - (C01r*C01r + C01i*C01i);
  float invdet = 1.f / det;
  float x0r = mx.x*invc, x0i = mx.y*invc, x1r = mx.z*invc, x1i = mx.w*invc;
  float ix0r = (C11*x0r - (C01r*x1r - C01i*x1i)) * invdet;
  float ix0i = (C11*x0i - (C01r*x1i + C01i*x1r)) * invdet;
  float ix1r = (C00*x1r - (C01r*x0r + C01i*x0i)) * invdet;
  float ix1i = (C00*x1i - (C01r*x0i - C01i*x0r)) * invdet;
#pragma unroll
  for (int sq = 0; sq < 4; sq++) {
    float vc = v[sq] * c;
    y[sq*2+0] = make_float2(vc*(R[sq].x*ix0r + R[sq].z*ix1r - R[sq].w*ix1i),
                            vc*(R[sq].x*ix0i + R[sq].z*ix1i + R[sq].w*ix1r));
    y[sq*2+1] = make_float2(vc*(R[sq].z*ix0r + R[sq].w*ix0i + R[sq].y*ix1r),
                            vc*(R[sq].z*ix0i - R[sq].w*ix0r + R[sq].y*ix1i));
  }
}

// ---- K3: EM apply + Hermitian fold, write Z (fp16), row stride ROWZ -------
__global__ __launch_bounds__(256) void k_apply(const float* __restrict__ spec,
                                               const float* __restrict__ mix,
                                               const unsigned int* __restrict__ c2max,
                                               const float* __restrict__ Rbuf,
                                               __half2* __restrict__ Z) {
  size_t idx = (size_t)blockIdx.x * 256 + threadIdx.x;
  if (idx >= (size_t)2 * TF * 1025) return;
  int k = (int)(idx % 1025);
  int r = (int)(idx / 1025);
  int t = r % TF, b = r / TF;
  int winid = b * 2 + (t >= WINF ? 1 : 0);
  float c = fmaxf(1.f, sqrtf(__uint_as_float(c2max[winid])) * 0.1f);
  float invc = 1.f / c, inv2c2 = 0.5f * invc * invc;
  size_t rowb = (size_t)(b * TF + t) * NB;
  int fB = 2048 - k;
  float2 yA[8], yB[8];
  em8(spec, mix, Rbuf, winid, c, invc, inv2c2, rowb + k,  k,  yA);
  em8(spec, mix, Rbuf, winid, c, invc, inv2c2, rowb + fB, fB, yB);
  float sn, cs;
  __sincosf((float)k * 0.0015339807878856412f /* pi/2048 */, &sn, &cs);
#pragma unroll
  for (int o = 0; o < 8; o++) {
    float2 Xa = yA[o], Xb = yB[o];
    if (k == 0) { Xa.y = 0.f; Xb.y = 0.f; }
    float Sx = Xa.x + Xb.x, Sy = Xa.y - Xb.y;
    float Dx = Xa.x - Xb.x, Dy = Xa.y + Xb.y;
    float sd = sn*Dx, cd = cs*Dy;
    float ci = cs*Dx - sn*Dy;
    int sid = (b * 4 + (o >> 1)) * 2 + (o & 1);
    size_t rowo = ((size_t)sid * TF + t) * ROWZ;
    Z[rowo + k] = __floats2half2_rn(0.5f*(Sx - sd - cd), 0.5f*(Sy + ci));
    if (k > 0)
      Z[rowo + 2048 - k] = __floats2half2_rn(0.5f*(Sx + sd + cd), 0.5f*(-Sy + ci));
  }
}

// ---- inverse DFT-8 (unnormalized, e^{+i}) ---------------------------------
__device__ __forceinline__ void dft8(const float2* x, float2* X) {
  const float S2 = 0.70710678118654752f;
  float2 t0 = cadd(x[0], x[4]), t1 = csub(x[0], x[4]);
  float2 t2 = cadd(x[2], x[6]), t3 = csub(x[2], x[6]);
  float2 E0 = cadd(t0, t2), E2 = csub(t0, t2);
  float2 E1 = make_float2(t1.x - t3.y, t1.y + t3.x);
  float2 E3 = make_float2(t1.x + t3.y, t1.y - t3.x);
  float2 u0 = cadd(x[1], x[5]), u1 = csub(x[1], x[5]);
  float2 u2 = cadd(x[3], x[7]), u3 = csub(x[3], x[7]);
  float2 O0 = cadd(u0, u2), O2 = csub(u0, u2);
  float2 O1 = make_float2(u1.x - u3.y, u1.y + u3.x);
  float2 O3 = make_float2(u1.x + u3.y, u1.y - u3.x);
  float2 R1 = make_float2(S2*(O1.x - O1.y), S2*(O1.x + O1.y));   // e^{i pi/4} O1
  float2 R2 = make_float2(-O2.y, O2.x);                          // i O2
  float2 R3 = make_float2(-S2*(O3.x + O3.y), S2*(O3.x - O3.y));  // e^{i 3pi/4} O3
  X[0] = cadd(E0, O0); X[4] = csub(E0, O0);
  X[1] = cadd(E1, R1); X[5] = csub(E1, R1);
  X[2] = cadd(E2, R2); X[6] = csub(E2, R2);
  X[3] = cadd(E3, R3); X[7] = csub(E3, R3);
}

// radix-8 Stockham stage from registers, NS=1 (no twiddles)
__device__ __forceinline__ void r8_reg(const float2* x, float2* dst, int tid) {
  float2 X[8];
  dft8(x, X);
  const int d = tid << 3;
#pragma unroll
  for (int n = 0; n < 8; n++) dst[PADI(d + n)] = X[n];
}

// radix-8 Stockham stage, IN PLACE, twiddles from LDS table
// tw[jm*7 + (m-1)] = e^{i*pi*jm*m/(4*NS)}
template<int NS>
__device__ __forceinline__ void r8stage_ip_t(float2* __restrict__ buf,
                                             const float2* __restrict__ tw, int tid) {
  const int q = tid;
  const int jm = q & (NS - 1);
  float2 x[8];
#pragma unroll
  for (int m = 0; m < 8; m++) x[m] = buf[PADI(q + (m << 8))];
  const float2* tr = tw + jm * 7;
#pragma unroll
  for (int m = 1; m < 8; m++) x[m] = cmul(x[m], tr[m - 1]);
  float2 X[8];
  dft8(x, X);
  __syncthreads();   // all reads complete before any write (same buffer)
  const int d = ((q - jm) << 3) + jm;
#pragma unroll
  for (int n = 0; n < 8; n++) buf[PADI(d + n * NS)] = X[n];
}

// final radix-4 stage (NS=512), UNWINDOWED fp16 store (window moved to gather)
__device__ __forceinline__ void r4_final(const float2* __restrict__ src,
                                         __half2* __restrict__ frow, int tid) {
  const float S2 = 0.70710678118654752f;
  float bsn, bcs;
  __sincosf((float)tid * 0.0030679615757712823f /* 2pi/2048 */, &bsn, &bcs);
  float2 w1 = make_float2(bcs, bsn);   // e^{i q pi/1024}, q=tid
#pragma unroll
  for (int qq = 0; qq < 2; qq++) {
    const int q = tid + (qq << 8);
    float2 v0 = src[PADI(q)];
    float2 v1 = src[PADI(q + 512)];
    float2 v2 = src[PADI(q + 1024)];
    float2 v3 = src[PADI(q + 1536)];
    float2 w2 = cmul(w1, w1);
    float2 w3 = cmul(w2, w1);
    v1 = cmul(v1, w1);
    v2 = cmul(v2, w2);
    v3 = cmul(v3, w3);
    float2 t0 = cadd(v0, v2), t1 = csub(v0, v2);
    float2 t2 = cadd(v1, v3), t3 = csub(v1, v3);
    float2 X0 = cadd(t0, t2);
    float2 X1 = make_float2(t1.x - t3.y, t1.y + t3.x);
    float2 X2 = csub(t0, t2);
    float2 X3 = make_float2(t1.x + t3.y, t1.y - t3.x);
    frow[q]        = __floats2half2_rn(X0.x, X0.y);
    frow[q + 512]  = __floats2half2_rn(X1.x, X1.y);
    frow[q + 1024] = __floats2half2_rn(X2.x, X2.y);
    frow[q + 1536] = __floats2half2_rn(X3.x, X3.y);
    if (qq == 0)
      w1 = make_float2((w1.x - w1.y) * S2, (w1.y + w1.x) * S2); // *= e^{i pi/4}
  }
}

// ---- K4a: one block per (sid, t): ifft of prefolded Z (radix 8,8,8,4) -----
__global__ __launch_bounds__(256, 6) void k_frames(__half2* __restrict__ ZF) {
  __shared__ float2 buf[2176];
  __shared__ float2 tw[504];
  const int tid = threadIdx.x;
  const int t = blockIdx.x % TF;
  const int sid = blockIdx.x / TF;
  const size_t row = ((size_t)sid * TF + t) * ROWZ;
  const unsigned* Zu = (const unsigned*)(ZF + row);

  // build twiddle table (once per block; visibility covered by sync below)
  for (int i = tid; i < 504; i += 256) {
    int jm, m; float scale;
    if (i < 56)  { jm = i / 7;        m = i % 7 + 1; scale = 0.09817477042468103f; }  // pi/32
    else         { int j = i - 56; jm = j / 7; m = j % 7 + 1; scale = 0.012271846303085129f; } // pi/256
    float sn, cs;
    __sincosf((float)(jm * m) * scale, &sn, &cs);
    tw[i] = make_float2(cs, sn);
  }

  // load prefolded Z straight into registers (coalesced)
  float2 x[8];
#pragma unroll
  for (int m = 0; m < 8; m++) x[m] = h2f2(Zu[tid + (m << 8)]);

  r8_reg(x, buf, tid);     // NS=1 write (no prior LDS content)
  __syncthreads();         // covers table build + buf
  r8stage_ip_t<8>(buf, tw, tid);
  __syncthreads();
  r8stage_ip_t<64>(buf, tw + 56, tid);
  __syncthreads();
  r4_final(buf, ZF + row, tid);   // NS=512 + store (in-place row)
}

// ---- K4b: gather overlap-add + window + wsum normalize (fused) ------------
// Frames are stored unwindowed/unscaled; gather applies win and divides by
// the numerically-computed wsum (exactly like the reference) — window evals
// hide under the kernel's 118 MB memory time.
__global__ __launch_bounds__(256) void k_gather(const __half2* __restrict__ frames,
                                                float* __restrict__ out) {
  const int sid = blockIdx.x / 599;
  const int o4 = (blockIdx.x % 599) * 256 + threadIdx.x;   // 153344 quads/sid
  const int n = 2048 + 4 * o4;
  const int tbase = n >> 10;
  float s0 = 0.f, s1 = 0.f, s2 = 0.f, s3 = 0.f;
  float w0 = 0.f, w1 = 0.f, w2 = 0.f, w3 = 0.f;
#pragma unroll
  for (int dt = 0; dt < 4; dt++) {
    int t = tbase - 3 + dt;
    if ((unsigned)t < (unsigned)TF) {
      int j = n - (t << 10);           // 0..4095, even
      float2 pk = *(const float2*)(frames + ((size_t)sid * TF + t) * ROWZ + (j >> 1));
      float2 va = h2f2(__float_as_uint(pk.x));
      float2 vb = h2f2(__float_as_uint(pk.y));
      float a0 = 0.5f - 0.5f * __cosf((float)j * W4096);
      float a1 = 0.5f - 0.5f * __cosf((float)(j + 1) * W4096);
      float a2 = 0.5f - 0.5f * __cosf((float)(j + 2) * W4096);
      float a3 = 0.5f - 0.5f * __cosf((float)(j + 3) * W4096);
      s0 += va.x * a0; s1 += va.y * a1; s2 += vb.x * a2; s3 += vb.y * a3;
      w0 += a0 * a0; w1 += a1 * a1; w2 += a2 * a2; w3 += a3 * a3;
    }
  }
  const float SC = 1.f / 2048.f;
  float i0 = SC / ((w0 > 1e-11f) ? w0 : 1.f);
  float i1 = SC / ((w1 > 1e-11f) ? w1 : 1.f);
  float i2 = SC / ((w2 > 1e-11f) ? w2 : 1.f);
  float i3 = SC / ((w3 > 1e-11f) ? w3 : 1.f);
  *(float4*)(out + (size_t)sid * ALEN + 4 * o4) =
      make_float4(s0 * i0, s1 * i1, s2 * i2, s3 * i3);
}

// ---- legacy fused path (fallback if ws too small) -------------------------
__device__ __forceinline__ float2 em_point_one(const float* __restrict__ spec,
    const float* __restrict__ mix, const float* __restrict__ Rbuf,
    const unsigned int* __restrict__ c2max, int b, int t, int f, int ssel, int ch) {
  int winid = b * 2 + (t >= WINF ? 1 : 0);
  float c = fmaxf(1.f, sqrtf(__uint_as_float(c2max[winid])) * 0.1f);
  float invc = 1.f / c, inv2c2 = 0.5f * invc * invc;
  size_t base = (size_t)(b * TF + t) * NB + f;
  const float4* sp = (const float4*)(spec + base * 8);
  float4 s0 = sp[0], s1 = sp[1];
  float4 mx = *(const float4*)(mix + base * 4);
  const float4* Rp = (const float4*)(Rbuf + ((size_t)winid * NB + f) * 16);
  float A0v[4] = {s0.x, s0.y, s0.z, s0.w};
  float A1v[4] = {s1.x, s1.y, s1.z, s1.w};
  float C00 = SQEPS, C11 = SQEPS, C01r = 0.f, C01i = 0.f;
  float vsel = 0.f; float4 Rsel = make_float4(0.f, 0.f, 0.f, 0.f);
#pragma unroll
  for (int sq = 0; sq < 4; sq++) {
    float4 R = Rp[sq];
    float v = (A0v[sq]*A0v[sq] + A1v[sq]*A1v[sq]) * inv2c2;
    C00 += v*R.x; C11 += v*R.y; C01r += v*R.z; C01i += v*R.w;
    if (sq == ssel) { vsel = v; Rsel = R; }
  }
  float det = C00*C11 - (C01r*C01r + C01i*C01i);
  float invdet = 1.f / det;
  float x0r = mx.x*invc, x0i = mx.y*invc, x1r = mx.z*invc, x1i = mx.w*invc;
  float ix0r = (C11*x0r - (C01r*x1r - C01i*x1i)) * invdet;
  float ix0i = (C11*x0i - (C01r*x1i + C01i*x1r)) * invdet;
  float ix1r = (C00*x1r - (C01r*x0r + C01i*x0i)) * invdet;
  float ix1i = (C00*x1i - (C01r*x0i - C01i*x0r)) * invdet;
  float vc = vsel * c;
  if (ch == 0)
    return make_float2(vc*(Rsel.x*ix0r + Rsel.z*ix1r - Rsel.w*ix1i),
                       vc*(Rsel.x*ix0i + Rsel.z*ix1i + Rsel.w*ix1r));
  return make_float2(vc*(Rsel.z*ix0r + Rsel.w*ix0i + Rsel.y*ix1r),
                     vc*(Rsel.z*ix0i - Rsel.w*ix0r + Rsel.y*ix1i));
}

template<int NS>
__device__ __forceinline__ void r4stage(const float2* __restrict__ src,
                                        float2* __restrict__ dst, int tid) {
#pragma unroll
  for (int qq = 0; qq < 2; qq++) {
    int q = tid + qq * 256;
    int jm = q & (NS - 1);
    float2 v0 = src[PADI(q)];
    float2 v1 = src[PADI(q + 512)];
    float2 v2 = src[PADI(q + 1024)];
    float2 v3 = src[PADI(q + 1536)];
    if constexpr (NS > 1) {
      float sn, cs;
      __sincosf((float)jm * (1.5707963267948966f / (float)NS), &sn, &cs);
      float2 w1 = make_float2(cs, sn);
      float2 w2 = cmul(w1, w1);
      float2 w3 = cmul(w2, w1);
      v1 = cmul(v1, w1);
      v2 = cmul(v2, w2);
      v3 = cmul(v3, w3);
    }
    float2 a0 = cadd(v0, v2), a1 = csub(v0, v2);
    float2 a2 = cadd(v1, v3), a3 = csub(v1, v3);
    int d = ((q - jm) << 2) + jm;
    dst[PADI(d)]        = cadd(a0, a2);
    dst[PADI(d + NS)]   = make_float2(a1.x - a3.y, a1.y + a3.x);
    dst[PADI(d + 2*NS)] = csub(a0, a2);
    dst[PADI(d + 3*NS)] = make_float2(a1.x + a3.y, a1.y - a3.x);
  }
}

__device__ __forceinline__ void r2stage(const float2* __restrict__ src,
                                        float2* __restrict__ dst, int tid) {
#pragma unroll
  for (int qq = 0; qq < 4; qq++) {
    int q = tid + qq * 256;
    float sn, cs;
    __sincosf((float)q * 0.003067961575771282f, &sn, &cs);
    float2 v0 = src[PADI(q)];
    float2 v1 = cmul(src[PADI(q + 1024)], make_float2(cs, sn));
    dst[PADI(q)]        = cadd(v0, v1);
    dst[PADI(q + 1024)] = csub(v0, v1);
  }
}

__global__ __launch_bounds__(256) void k_istft_fused(const float* __restrict__ spec,
        const float* __restrict__ mix, const unsigned int* __restrict__ c2max,
        const float* __restrict__ Rbuf, float* __restrict__ out) {
  __shared__ float2 bufA[2176];
  __shared__ float2 bufB[2176];
  const int tid = threadIdx.x;
  const int u = blockIdx.x % 150;
  const int sid = blockIdx.x / 150;
  const int b = sid >> 3;
  const int s = (sid >> 1) & 3;
  const int ch = sid & 1;
  float acc[16], wsm[16];
#pragma unroll
  for (int k = 0; k < 16; k++) { acc[k] = 0.f; wsm[k] = 0.f; }
  const int t0 = max(0, 4 * u - 1);
  const int t1 = min(TF - 1, 4 * u + 5);
  const int M0 = 2048 + u * 4096;
  for (int t = t0; t <= t1; ++t) {
    for (int k = tid; k < 2048; k += 256) {
      float2 Xa = em_point_one(spec, mix, Rbuf, c2max, b, t, k, s, ch);
      float2 Xb = em_point_one(spec, mix, Rbuf, c2max, b, t, 2048 - k, s, ch);
      if (k == 0) { Xa.y = 0.f; Xb.y = 0.f; }
      float Sx = Xa.x + Xb.x, Sy = Xa.y - Xb.y;
      float Dx = Xa.x - Xb.x, Dy = Xa.y + Xb.y;
      float sn, cs;
      __sincosf((float)k * 0.0015339807878856412f, &sn, &cs);
      bufA[PADI(k)] = make_float2(0.5f * (Sx - sn*Dx - cs*Dy),
                                  0.5f * (Sy + cs*Dx - sn*Dy));
    }
    __syncthreads();
    r4stage<1>(bufA, bufB, tid);   __syncthreads();
    r4stage<4>(bufB, bufA, tid);   __syncthreads();
    r4stage<16>(bufA, bufB, tid);  __syncthreads();
    r4stage<64>(bufB, bufA, tid);  __syncthreads();
    r4stage<256>(bufA, bufB, tid); __syncthreads();
    r2stage(bufB, bufA, tid);      __syncthreads();
    const int delta = M0 - t * HOP;
#pragma unroll
    for (int k2 = 0; k2 < 16; k2++) {
      int n = tid + 256 * k2 + delta;
      if (n >= 0 && n < NFFT) {
        float2 z = bufA[PADI(n >> 1)];
        float xn = (n & 1) ? z.y : z.x;
        float wn = 0.5f - 0.5f * __cosf((float)n * W4096);
        acc[k2] += xn * wn * (1.f / 2048.f);
        wsm[k2] += wn * wn;
      }
    }
    __syncthreads();
  }
#pragma unroll
  for (int k2 = 0; k2 < 16; k2++) {
    size_t o = (size_t)u * 4096 + tid + 256 * k2;
    if (o < (size_t)ALEN) {
      float wsv = wsm[k2];
      out[(size_t)sid * ALEN + o] = acc[k2] / (wsv > 1e-11f ? wsv : 1.f);
    }
  }
}

extern "C" void kernel_launch(void* const* d_in, const int* in_sizes, int n_in,
                              void* d_out, int out_size, void* d_ws, size_t ws_size,
                              hipStream_t stream) {
  const float* spec = (const float*)d_in[0];
  const float* mix  = (const float*)d_in[1];
  float* out = (float*)d_out;
  unsigned char* ws = (unsigned char*)d_ws;
  unsigned int* c2max = (unsigned int*)ws;         // 16 B
  float* Rbuf = (float*)(ws + 256);                // 524544 B
  __half2* Z = (__half2*)(ws + 524800);            // 16*600*2048*4 = 78.6 MB
  float* part = (float*)(ws + 524800);             // 10.5 MB, consumed before Z written
  const size_t needZ = 524800 + (size_t)16 * TF * ROWZ * 4;

  k_init<<<1, 256, 0, stream>>>(c2max);
  if (ws_size >= needZ) {
    k_rmat_part<<<4 * RCH * 9, 256, 0, stream>>>(spec, mix, part, c2max);
    k_rmat_red<<<(4 * NB * 4 + 255) / 256, 256, 0, stream>>>(part, c2max, Rbuf);
    int total = 2 * TF * 1025;
    k_apply<<<(total + 255) / 256, 256, 0, stream>>>(spec, mix, c2max, Rbuf, Z);
    k_frames<<<16 * TF, 256, 0, stream>>>(Z);
    k_gather<<<16 * 599, 256, 0, stream>>>(Z, out);
  } else {
    k_maxred<<<256, 256, 0, stream>>>(mix, c2max);
    k_rmat<<<NB, 256, 0, stream>>>(spec, mix, c2max, Rbuf);
    k_istft_fused<<<16 * 150, 256, 0, stream>>>(spec, mix, c2max, Rbuf, out);
  }
}